// Round 7
// baseline (183.955 us; speedup 1.0000x reference)
//
#include <hip/hip_runtime.h>
#include <hip/hip_bf16.h>

#define B_ 4
#define T_ 2048
#define C_ 1024
#define H_ 16
#define D_ 64
#define C3 3072

typedef __bf16 bf16x8 __attribute__((ext_vector_type(8)));
typedef __bf16 bf16x4 __attribute__((ext_vector_type(4)));
typedef float f32x2 __attribute__((ext_vector_type(2)));
typedef float f32x4 __attribute__((ext_vector_type(4)));
typedef float f32x16 __attribute__((ext_vector_type(16)));
typedef unsigned u32x4 __attribute__((ext_vector_type(4)));

// 0.125 (1/sqrt(D)) * log2(e): softmax computed in exp2 domain; folded into Q at GEMM1 epilogue
#define SCALE_LOG2E 0.1803368801111244f

__device__ __forceinline__ void gload_lds16(const void* g, void* lds) {
  __builtin_amdgcn_global_load_lds((const __attribute__((address_space(1))) void*)g,
                                   (__attribute__((address_space(3))) void*)lds, 16, 0, 0);
}

// byte offset into a tile with 128-byte rows (64 bf16), XOR-swizzled 16B chunks
__device__ __forceinline__ int swz128(int row, int chunk) {
  return row * 128 + ((chunk ^ (row & 7)) << 4);
}

__device__ __forceinline__ unsigned cvt_pk_bf16(float a, float b) {
  unsigned r;
  asm("v_cvt_pk_bf16_f32 %0, %1, %2" : "=v"(r) : "v"(a), "v"(b));
  return r;
}

__device__ __forceinline__ void pl32swap(unsigned& x, unsigned& y) {
  asm volatile("v_permlane32_swap_b32 %0, %1" : "+v"(x), "+v"(y));
}

__device__ __forceinline__ float fmax3(float a, float b, float c) {
  float d;
  asm("v_max3_f32 %0, %1, %2, %3" : "=v"(d) : "v"(a), "v"(b), "v"(c));
  return d;
}

__device__ __forceinline__ f32x2 pk_add(f32x2 a, f32x2 b) {
  f32x2 d;
  asm("v_pk_add_f32 %0, %1, %2" : "=v"(d) : "v"(a), "v"(b));
  return d;
}

// ---------------- cast x: fp32 -> bf16, vectorized ----------------
__global__ void cast_x_kernel(const float* __restrict__ in, __bf16* __restrict__ out, int n4) {
  int i = blockIdx.x * blockDim.x + threadIdx.x;
  if (i >= n4) return;
  float4 v = ((const float4*)in)[i];
  bf16x4 o;
  o.x = (__bf16)v.x; o.y = (__bf16)v.y; o.z = (__bf16)v.z; o.w = (__bf16)v.w;
  ((bf16x4*)out)[i] = o;
}

// ---------------- transpose + cast: fp32 [K][N] -> bf16 [N][K] ----------------
__global__ void transpose_cast_kernel(const float* __restrict__ in, __bf16* __restrict__ out,
                                      int K, int N) {
  __shared__ float tile[32][33];
  int kb = blockIdx.y * 32, nb = blockIdx.x * 32;
  int tx = threadIdx.x, ty = threadIdx.y;
#pragma unroll
  for (int i = 0; i < 4; i++) {
    int r = ty + i * 8;
    tile[r][tx] = in[(size_t)(kb + r) * N + nb + tx];
  }
  __syncthreads();
#pragma unroll
  for (int i = 0; i < 4; i++) {
    int r = ty + i * 8;
    out[(size_t)(nb + r) * K + kb + tx] = (__bf16)tile[tx][r];
  }
}

// ---------------- 256x256 8-phase GEMM: C[M,N] = A[M,K] * Bt[N,K]^T ----------------
// 512 threads = 8 waves (2M x 4N); per-wave output 128x64; BK=64; 128 KiB LDS (2 dbuf).
// Stage units per 4-phase group: sub0 {A-q0,B-q0} (4 loads/wave), sub1 {B-q1} (2),
// sub2 {A-q1} (2), sub3 none.  Every unit consumed >= 4 phases after issue.
// Counted waits (invariant: before phase q's end barrier, loads from phases <= q-3 done):
// N(q) = L(q-2)+L(q-1) -> vmcnt [2,4,6,4] at subs [0,1,2,3].  Never 0 in-loop (T4).
// MODE 1: f32 out.  MODE 2: qkv mode (Q cols scaled; V cols transposed into vT).
template <int MODE>
__global__ __launch_bounds__(512) void gemm_bt_kernel(const __bf16* __restrict__ A,
                                                      const __bf16* __restrict__ Bt,
                                                      __bf16* __restrict__ Cb,
                                                      float* __restrict__ Cf,
                                                      __bf16* __restrict__ vT,
                                                      int M, int N, int K) {
  __shared__ __align__(16) char lds[131072];  // [2 buf][ A 32KB | B 32KB ]
  int tid = threadIdx.x, w = tid >> 6, l = tid & 63;
  int wm = w >> 2, wn = w & 3;
  int lr = l & 15, lhi = l >> 4;

  // XCD-chunked swizzle (nwg % 8 == 0 for all uses)
  int gx = gridDim.x;
  int nwg = gx * gridDim.y;
  int orig = blockIdx.y * gx + blockIdx.x;
  int cpx = nwg >> 3;
  int swz = (orig & 7) * cpx + (orig >> 3);
  int bx = swz % gx, by = swz / gx;
  int m0 = by * 256, n0 = bx * 256;

  const __bf16* Abase = A + (size_t)m0 * K;
  const __bf16* Bbase = Bt + (size_t)n0 * K;

  f32x4 acc[8][4];
#pragma unroll
  for (int m = 0; m < 8; m++)
#pragma unroll
    for (int n = 0; n < 4; n++) acc[m][n] = (f32x4){0.f, 0.f, 0.f, 0.f};

  int nKtot = K >> 6;  // 16
  int lrow = l >> 3;
  int cgs = (l & 7) ^ lrow;  // pre-swizzled chunk (row&7 == l>>3 for 8-row blocks)

  // stage one unit (16 KB): u=0 A-q0, u=1 B-q0, u=2 B-q1, u=3 A-q1.
  // kt clamped (dummy re-stage) so the per-phase load ledger stays uniform.
  auto stageu = [&](int u, int kt, int bufb) {
    if (kt >= nKtot) kt = nKtot - 1;
    int k0 = kt << 6;
    char* dA = lds + bufb * 65536;
    char* dB = dA + 32768;
#pragma unroll
    for (int jj = 0; jj < 2; jj++) {
      int j = w * 2 + jj;
      if (u == 0 || u == 3) {
        int q = (u == 3);
        int rowbase = (j >> 3) * 128 + q * 64 + (j & 7) * 8;
        gload_lds16(Abase + (size_t)(rowbase + lrow) * K + k0 + cgs * 8, dA + rowbase * 128);
      } else {
        int q = (u == 2);
        int rowbase = (j >> 2) * 64 + q * 32 + (j & 3) * 8;
        gload_lds16(Bbase + (size_t)(rowbase + lrow) * K + k0 + cgs * 8, dB + rowbase * 128);
      }
    }
  };

  // prologue: all 4 units of K-tile 0 into buf 0; publish units A-q0/B-q0 for phase 0
  stageu(0, 0, 0);
  stageu(1, 0, 0);
  stageu(2, 0, 0);
  stageu(3, 0, 0);
  asm volatile("s_waitcnt vmcnt(4)" ::: "memory");
  __builtin_amdgcn_s_barrier();

  int nIter = nKtot >> 1;  // 8
  for (int it = 0; it < nIter; it++) {
    int tS1 = 2 * it + 1;  // staged during phases 0-3 -> buf1, read phases 4-7
    int tS2 = 2 * it + 2;  // staged during phases 4-7 -> buf0, read next iter 0-3
#pragma unroll
    for (int ph = 0; ph < 8; ph++) {
      const int grp = ph >> 2;  // 0: read buf0, 1: read buf1
      const int sub = ph & 3;
      const int QM = sub >> 1, QN = sub & 1;
      // counted waits: N(q) = L(q-2)+L(q-1), L = [4,2,2,0]
      if (sub == 0)      asm volatile("s_waitcnt vmcnt(2)" ::: "memory");
      else if (sub == 1) asm volatile("s_waitcnt vmcnt(4)" ::: "memory");
      else if (sub == 2) asm volatile("s_waitcnt vmcnt(6)" ::: "memory");
      else               asm volatile("s_waitcnt vmcnt(4)" ::: "memory");
      char* lA = lds + grp * 65536;
      char* lB = lA + 32768;
      bf16x8 af[4][2], bfr[2][2];
#pragma unroll
      for (int mf = 0; mf < 4; mf++)
#pragma unroll
        for (int kk = 0; kk < 2; kk++)
          af[mf][kk] =
              *(const bf16x8*)(lA + swz128(wm * 128 + QM * 64 + mf * 16 + lr, kk * 4 + lhi));
#pragma unroll
      for (int nf = 0; nf < 2; nf++)
#pragma unroll
        for (int kk = 0; kk < 2; kk++)
          bfr[nf][kk] =
              *(const bf16x8*)(lB + swz128(wn * 64 + QN * 32 + nf * 16 + lr, kk * 4 + lhi));
      // stage this phase's unit(s) into the buffer NOT being read this group
      {
        int tS = grp == 0 ? tS1 : tS2;
        int dstb = grp == 0 ? 1 : 0;
        if (sub == 0) { stageu(0, tS, dstb); stageu(1, tS, dstb); }
        else if (sub == 1) stageu(2, tS, dstb);
        else if (sub == 2) stageu(3, tS, dstb);
      }
      __builtin_amdgcn_s_barrier();
      __builtin_amdgcn_s_setprio(1);
#pragma unroll
      for (int kk = 0; kk < 2; kk++)
#pragma unroll
        for (int mf = 0; mf < 4; mf++)
#pragma unroll
          for (int nf = 0; nf < 2; nf++)
            acc[QM * 4 + mf][QN * 2 + nf] = __builtin_amdgcn_mfma_f32_16x16x32_bf16(
                af[mf][kk], bfr[nf][kk], acc[QM * 4 + mf][QN * 2 + nf], 0, 0, 0);
      __builtin_amdgcn_s_setprio(0);
      __builtin_amdgcn_s_barrier();
    }
  }

  if (MODE == 2 && n0 >= 2048) {
    // V third: write transposed to vT (m-panel never straddles batch: 2048 % 256 == 0)
    int bb = m0 >> 11;
    int tb = (m0 & 2047) + wm * 128 + lhi * 4;
#pragma unroll
    for (int n = 0; n < 4; n++) {
      int vcol = (n0 - 2048) + wn * 64 + n * 16 + lr;
      __bf16* vp = vT + ((size_t)bb * 1024 + vcol) * T_;
#pragma unroll
      for (int m = 0; m < 8; m++) {
        bf16x4 pv;
#pragma unroll
        for (int i = 0; i < 4; i++) pv[i] = (__bf16)acc[m][n][i];
        *(bf16x4*)(vp + tb + m * 16) = pv;
      }
    }
    return;
  }

  float oscale = (MODE == 2 && n0 < 1024) ? SCALE_LOG2E : 1.0f;
#pragma unroll
  for (int m = 0; m < 8; m++)
#pragma unroll
    for (int n = 0; n < 4; n++)
#pragma unroll
      for (int i = 0; i < 4; i++) {
        int rg = m0 + wm * 128 + m * 16 + lhi * 4 + i;
        int cg2 = n0 + wn * 64 + n * 16 + lr;
        if (MODE == 1)
          Cf[(size_t)rg * N + cg2] = acc[m][n][i];
        else
          Cb[(size_t)rg * N + cg2] = (__bf16)(acc[m][n][i] * oscale);
      }
}

// ---------------- causal flash attention, swapped-QK^T 32x32, double-buffered ----------------
// 1024 blocks; wave owns 32 q rows, lane owns 1 q row (full P row in regs).
// Q is pre-scaled by SCALE_LOG2E (folded into GEMM1 epilogue) -> scores already in log2 units.
__global__ __launch_bounds__(256) void attn_kernel(const __bf16* __restrict__ qkv,
                                                   const __bf16* __restrict__ vT,
                                                   __bf16* __restrict__ y) {
  __shared__ __align__(16) char lds[2][16384];  // [buf][ K(8KB,[kv][d]) | V^T(8KB,[d][kv]) ]
  int tid = threadIdx.x, w = tid >> 6, l = tid & 63;

  // work-balance map: 4 co-resident blocks per CU (bids mod-256 apart) sum to const work;
  // all qb of one bh share an XCD (bid&7 == bh&7) for K/V L2 reuse.
  int g = blockIdx.x >> 6, bh = blockIdx.x & 63;
  int q2 = g >> 2;
  int qb = (q2 & 1) ? ((q2 == 1) ? g + 4 : g - 12) : (15 - g);
  int b = bh >> 4, h = bh & 15;
  size_t base = (size_t)b * T_ * C3;
  int lq = l & 31, hi = l >> 5;
  int qrow = qb * 128 + w * 32 + lq;
  int q0w = qb * 128 + w * 32;

  // staging source pointers (pre-swizzled chunk)
  int lrow = l >> 3;
  int cg = (l & 7) ^ (lrow & 7);
  const __bf16* kptr = qkv + base + (size_t)(w * 16 + lrow) * C3 + C_ + h * D_ + cg * 8;
  const __bf16* vptr = vT + ((size_t)bh * D_ + w * 16 + lrow) * T_ + cg * 8;

  // Q as B-operand fragments (pre-scaled)
  bf16x8 qf[4];
  {
    const __bf16* qp = qkv + base + (size_t)qrow * C3 + h * D_;
#pragma unroll
    for (int c = 0; c < 4; c++) qf[c] = *(const bf16x8*)(qp + c * 16 + hi * 8);
  }

  f32x16 zacc;
#pragma unroll
  for (int i = 0; i < 16; i++) zacc[i] = 0.f;
  f32x16 o[2];
  o[0] = zacc; o[1] = zacc;
  float mrun = -__builtin_inff(), lrun = 0.f;

  int nt = 2 * qb + 2;

  // prologue: stage tile 0 into buf 0
  {
    char* kb = &lds[0][0];
    char* vb = &lds[0][8192];
    gload_lds16(kptr, kb + w * 2048);
    gload_lds16(kptr + 8 * C3, kb + w * 2048 + 1024);
    gload_lds16(vptr, vb + w * 2048);
    gload_lds16(vptr + 8 * T_, vb + w * 2048 + 1024);
  }

  for (int kt = 0; kt < nt; kt++) {
    int buf = kt & 1;
    __syncthreads();  // drains my stage of buf[kt&1]; all waves done reading buf^1
    if (kt + 1 < nt) {
      char* kb = &lds[buf ^ 1][0];
      char* vb = &lds[buf ^ 1][8192];
      const __bf16* kp = kptr + (size_t)(kt + 1) * 64 * C3;
      const __bf16* vp = vptr + (kt + 1) * 64;
      gload_lds16(kp, kb + w * 2048);
      gload_lds16(kp + 8 * C3, kb + w * 2048 + 1024);
      gload_lds16(vp, vb + w * 2048);
      gload_lds16(vp + 8 * T_, vb + w * 2048 + 1024);
    }
    if (kt * 64 > q0w + 31) continue;  // wave fully below this kv tile
    char* kb = &lds[buf][0];
    char* vb = &lds[buf][8192];

    // S^T[kv][q] = K · Q^T : lane holds 32 kv values of its q row (log2 units)
    f32x16 s[2];
    __builtin_amdgcn_s_setprio(1);
#pragma unroll
    for (int b2 = 0; b2 < 2; b2++) {
      bf16x8 kf0 = *(const bf16x8*)(kb + swz128(b2 * 32 + lq, hi));
      s[b2] = __builtin_amdgcn_mfma_f32_32x32x16_bf16(kf0, qf[0], zacc, 0, 0, 0);
#pragma unroll
      for (int c = 1; c < 4; c++) {
        bf16x8 kf = *(const bf16x8*)(kb + swz128(b2 * 32 + lq, 2 * c + hi));
        s[b2] = __builtin_amdgcn_mfma_f32_32x32x16_bf16(kf, qf[c], s[b2], 0, 0, 0);
      }
    }
    __builtin_amdgcn_s_setprio(0);

    // causal mask (diagonal-straddling tiles only)
    if (kt * 64 + 63 > q0w) {
#pragma unroll
      for (int b2 = 0; b2 < 2; b2++)
#pragma unroll
        for (int r = 0; r < 16; r++) {
          int kv = kt * 64 + b2 * 32 + ((r & 3) + 8 * (r >> 2)) + 4 * hi;
          if (kv > qrow) s[b2][r] = -1e30f;
        }
    }

    // row max: max3 tree (17 ops) + one cross-half swap
    {
      auto xi = [&](int i) -> float { return i < 16 ? s[0][i] : s[1][i - 16]; };
      float t10[11];
#pragma unroll
      for (int g3 = 0; g3 < 10; g3++) t10[g3] = fmax3(xi(3 * g3), xi(3 * g3 + 1), xi(3 * g3 + 2));
      t10[10] = fmaxf(xi(30), xi(31));
      float u0 = fmax3(t10[0], t10[1], t10[2]);
      float u1 = fmax3(t10[3], t10[4], t10[5]);
      float u2 = fmax3(t10[6], t10[7], t10[8]);
      float u3 = fmaxf(t10[9], t10[10]);
      float tl = fmaxf(fmax3(u0, u1, u2), u3);
      float tmax = fmaxf(tl, __shfl_xor(tl, 32));

      // defer-max (T13): only rescale when some lane's max grew past threshold
      if (!__all(tmax - mrun <= 8.0f)) {
        float mnew = fmaxf(mrun, tmax);
        float al = __builtin_amdgcn_exp2f(mrun - mnew);
        mrun = mnew;
        lrun *= al;
#pragma unroll
        for (int d = 0; d < 2; d++)
#pragma unroll
          for (int i = 0; i < 16; i++) o[d][i] *= al;
      }
    }

    // p = 2^(s - m)
#pragma unroll
    for (int b2 = 0; b2 < 2; b2++)
#pragma unroll
      for (int r = 0; r < 16; r++) s[b2][r] = __builtin_amdgcn_exp2f(s[b2][r] - mrun);

    // row sum: packed-f32 tree (15 pk_add) + one cross-half swap
    {
      f32x2 p8[8];
#pragma unroll
      for (int g3 = 0; g3 < 8; g3++) {
        f32x2 a = {s[0][2 * g3], s[0][2 * g3 + 1]};
        f32x2 b2v = {s[1][2 * g3], s[1][2 * g3 + 1]};
        p8[g3] = pk_add(a, b2v);
      }
#pragma unroll
      for (int g3 = 0; g3 < 4; g3++) p8[g3] = pk_add(p8[g3], p8[g3 + 4]);
      p8[0] = pk_add(p8[0], p8[2]);
      p8[1] = pk_add(p8[1], p8[3]);
      p8[0] = pk_add(p8[0], p8[1]);
      float rs = p8[0][0] + p8[0][1];
      lrun += rs + __shfl_xor(rs, 32);
    }

    // P^T -> B-operand fragments via cvt_pk + permlane32_swap (no LDS)
    bf16x8 pa[4];
#pragma unroll
    for (int b2 = 0; b2 < 2; b2++) {
      unsigned wg[4][2];
#pragma unroll
      for (int gg = 0; gg < 4; gg++) {
        wg[gg][0] = cvt_pk_bf16(s[b2][4 * gg + 0], s[b2][4 * gg + 1]);
        wg[gg][1] = cvt_pk_bf16(s[b2][4 * gg + 2], s[b2][4 * gg + 3]);
      }
#pragma unroll
      for (int cp = 0; cp < 2; cp++) {
        unsigned x0 = wg[2 * cp][0], x1 = wg[2 * cp][1];
        unsigned y0 = wg[2 * cp + 1][0], y1 = wg[2 * cp + 1][1];
        pl32swap(x0, y0);
        pl32swap(x1, y1);
        union { u32x4 u; bf16x8 hh; } uu;
        uu.u = (u32x4){x0, x1, y0, y1};
        pa[b2 * 2 + cp] = uu.hh;
      }
    }

    // O^T[d][q] += V^T · P^T
    __builtin_amdgcn_s_setprio(1);
#pragma unroll
    for (int db = 0; db < 2; db++)
#pragma unroll
      for (int c = 0; c < 4; c++) {
        bf16x8 vf = *(const bf16x8*)(vb + swz128(db * 32 + lq, 2 * c + hi));
        o[db] = __builtin_amdgcn_mfma_f32_32x32x16_bf16(vf, pa[c], o[db], 0, 0, 0);
      }
    __builtin_amdgcn_s_setprio(0);
  }

  // epilogue: lane owns q-row qrow; d = db*32 + 8*rr + 4*hi + i
  float inv = 1.f / lrun;
  __bf16* yp = y + (size_t)(b * T_ + qrow) * C_ + h * D_;
#pragma unroll
  for (int db = 0; db < 2; db++)
#pragma unroll
    for (int rr = 0; rr < 4; rr++) {
      bf16x4 ov;
#pragma unroll
      for (int i = 0; i < 4; i++) ov[i] = (__bf16)(o[db][rr * 4 + i] * inv);
      *(bf16x4*)(yp + db * 32 + rr * 8 + hi * 4) = ov;
    }
}

extern "C" void kernel_launch(void* const* d_in, const int* in_sizes, int n_in,
                              void* d_out, int out_size, void* d_ws, size_t ws_size,
                              hipStream_t stream) {
  const float* x = (const float*)d_in[0];
  const float* Wa = (const float*)d_in[1];
  const float* Wp = (const float*)d_in[2];
  float* out = (float*)d_out;
  char* ws = (char*)d_ws;

  // xb and yb share storage (xb dead after GEMM1, yb born after GEMM1)
  __bf16* xb  = (__bf16*)(ws);                 // 16 MB
  __bf16* yb  = (__bf16*)(ws);                 // 16 MB (aliases xb)
  __bf16* wat = (__bf16*)(ws + 16777216);      // 6 MB
  __bf16* wpt = (__bf16*)(ws + 23068672);      // 2 MB
  __bf16* qkv = (__bf16*)(ws + 25165824);      // 48 MB (V third unused)
  __bf16* vT  = (__bf16*)(ws + 75497472);      // 16 MB

  cast_x_kernel<<<8192, 256, 0, stream>>>(x, xb, (B_ * T_ * C_) / 4);
  transpose_cast_kernel<<<dim3(C3 / 32, C_ / 32), dim3(32, 8), 0, stream>>>(Wa, wat, C_, C3);
  transpose_cast_kernel<<<dim3(C_ / 32, C_ / 32), dim3(32, 8), 0, stream>>>(Wp, wpt, C_, C_);

  // qkv = x @ W_attn; Q cols pre-scaled, V cols written transposed to vT
  gemm_bt_kernel<2><<<dim3(C3 / 256, (B_ * T_) / 256), 512, 0, stream>>>(
      xb, wat, qkv, nullptr, vT, B_ * T_, C3, C_);

  attn_kernel<<<dim3(1024), 256, 0, stream>>>(qkv, vT, yb);

  gemm_bt_kernel<1><<<dim3(C_ / 256, (B_ * T_) / 256), 512, 0, stream>>>(
      yb, wpt, nullptr, out, nullptr, B_ * T_, C_, C_);
}

// Round 9
// 151.578 us; speedup vs baseline: 1.2136x; 1.2136x over previous
//
#include <hip/hip_runtime.h>
#include <hip/hip_bf16.h>

#define B_ 4
#define T_ 2048
#define C_ 1024
#define H_ 16
#define D_ 64
#define C3 3072

typedef __bf16 bf16x8 __attribute__((ext_vector_type(8)));
typedef __bf16 bf16x4 __attribute__((ext_vector_type(4)));
typedef float f32x2 __attribute__((ext_vector_type(2)));
typedef float f32x4 __attribute__((ext_vector_type(4)));
typedef float f32x16 __attribute__((ext_vector_type(16)));
typedef unsigned u32x4 __attribute__((ext_vector_type(4)));

// 0.125 (1/sqrt(D)) * log2(e): softmax computed in exp2 domain; folded into Q at GEMM1 epilogue
#define SCALE_LOG2E 0.1803368801111244f

__device__ __forceinline__ void gload_lds16(const void* g, void* lds) {
  __builtin_amdgcn_global_load_lds((const __attribute__((address_space(1))) void*)g,
                                   (__attribute__((address_space(3))) void*)lds, 16, 0, 0);
}

// byte offset into a tile with 128-byte rows (64 bf16), XOR-swizzled 16B chunks
__device__ __forceinline__ int swz128(int row, int chunk) {
  return row * 128 + ((chunk ^ (row & 7)) << 4);
}

__device__ __forceinline__ unsigned cvt_pk_bf16(float a, float b) {
  unsigned r;
  asm("v_cvt_pk_bf16_f32 %0, %1, %2" : "=v"(r) : "v"(a), "v"(b));
  return r;
}

__device__ __forceinline__ void pl32swap(unsigned& x, unsigned& y) {
  asm volatile("v_permlane32_swap_b32 %0, %1" : "+v"(x), "+v"(y));
}

__device__ __forceinline__ float fmax3(float a, float b, float c) {
  float d;
  asm("v_max3_f32 %0, %1, %2, %3" : "=v"(d) : "v"(a), "v"(b), "v"(c));
  return d;
}

__device__ __forceinline__ f32x2 pk_add(f32x2 a, f32x2 b) {
  f32x2 d;
  asm("v_pk_add_f32 %0, %1, %2" : "=v"(d) : "v"(a), "v"(b));
  return d;
}

// ---------------- fused prep: cast x (blocks 0..8191), transpose Wa (..11263), Wp (..12287) ----
__global__ __launch_bounds__(256) void prep_kernel(const float* __restrict__ x,
                                                   const float* __restrict__ Wa,
                                                   const float* __restrict__ Wp,
                                                   __bf16* __restrict__ xb,
                                                   __bf16* __restrict__ wat,
                                                   __bf16* __restrict__ wpt) {
  __shared__ float tile[32][33];
  int bid = blockIdx.x, tid = threadIdx.x;
  if (bid < 8192) {
    int i = bid * 256 + tid;
    float4 v = ((const float4*)x)[i];
    bf16x4 o;
    o.x = (__bf16)v.x; o.y = (__bf16)v.y; o.z = (__bf16)v.z; o.w = (__bf16)v.w;
    ((bf16x4*)xb)[i] = o;
    return;
  }
  const float* in;
  __bf16* out;
  int N, bx, by;
  if (bid < 11264) {
    int lb = bid - 8192;
    in = Wa; out = wat; N = C3;
    bx = lb % 96; by = lb / 96;
  } else {
    int lb = bid - 11264;
    in = Wp; out = wpt; N = C_;
    bx = lb & 31; by = lb >> 5;
  }
  int K = C_;
  int kb = by * 32, nb = bx * 32;
  int tx = tid & 31, ty = tid >> 5;
#pragma unroll
  for (int i = 0; i < 4; i++) {
    int r = ty + i * 8;
    tile[r][tx] = in[(size_t)(kb + r) * N + nb + tx];
  }
  __syncthreads();
#pragma unroll
  for (int i = 0; i < 4; i++) {
    int r = ty + i * 8;
    out[(size_t)(nb + r) * K + kb + tx] = (__bf16)tile[tx][r];
  }
}

// ---------------- GEMM: C[M,N] = A[M,K] * Bt[N,K]^T  (bf16 in, f32 acc) ----------------
// Double-buffered LDS, one barrier per K-step (stage t+1 after barrier, drained next iter).
// MODE 1: f32 row-major out.
// MODE 2: qkv mode — Q cols (<1024) scaled by SCALE_LOG2E into Cb; K cols into Cb;
//         V cols (>=2048) written transposed into vT[(b*1024 + vcol)][t].
template <int MODE>
__global__ __launch_bounds__(256) void gemm_bt_kernel(const __bf16* __restrict__ A,
                                                      const __bf16* __restrict__ Bt,
                                                      __bf16* __restrict__ Cb,
                                                      float* __restrict__ Cf,
                                                      __bf16* __restrict__ vT,
                                                      int M, int N, int K) {
  __shared__ __align__(16) char lds[2][32768];  // [buf][ A 16KB | B 16KB ]
  int tid = threadIdx.x, w = tid >> 6, l = tid & 63;
  // XCD-chunked swizzle (nwg % 8 == 0 for all uses)
  int gx = gridDim.x;
  int nwg = gx * gridDim.y;
  int orig = blockIdx.y * gx + blockIdx.x;
  int cpx = nwg >> 3;
  int swz = (orig & 7) * cpx + (orig >> 3);
  int bx = swz % gx, by = swz / gx;
  int m0 = by * 128, n0 = bx * 128;
  int wr = w >> 1, wc = w & 1;
  int lr = l & 15, lhi = l >> 4;

  int srow = l >> 3;              // staging: row within 8-row quad
  int cg = (l & 7) ^ (srow & 7);  // pre-swizzled global chunk

  f32x4 acc[4][4];
#pragma unroll
  for (int m = 0; m < 4; m++)
#pragma unroll
    for (int n = 0; n < 4; n++) acc[m][n] = (f32x4){0.f, 0.f, 0.f, 0.f};

  auto stage = [&](int kt, int buf) {
    int k0 = kt << 6;
    char* la = &lds[buf][0];
    char* lb = &lds[buf][16384];
#pragma unroll
    for (int jj = 0; jj < 4; jj++) {
      int q = w * 4 + jj;
      int row = q * 8 + srow;
      gload_lds16(A + (size_t)(m0 + row) * K + k0 + cg * 8, la + q * 1024);
      gload_lds16(Bt + (size_t)(n0 + row) * K + k0 + cg * 8, lb + q * 1024);
    }
  };

  int nK = K >> 6;
  stage(0, 0);  // prologue

  for (int kt = 0; kt < nK; kt++) {
    int buf = kt & 1;
    __syncthreads();  // drains my tile-kt loads (issued last iter); all waves done reading buf^1
    if (kt + 1 < nK) stage(kt + 1, buf ^ 1);
    char* la = &lds[buf][0];
    char* lb = &lds[buf][16384];

    bf16x8 af[4][2], bfr[4][2];
#pragma unroll
    for (int m = 0; m < 4; m++) {
      int r = wr * 64 + m * 16 + lr;
#pragma unroll
      for (int kc = 0; kc < 2; kc++)
        af[m][kc] = *(const bf16x8*)(la + swz128(r, kc * 4 + lhi));
    }
#pragma unroll
    for (int n = 0; n < 4; n++) {
      int r = wc * 64 + n * 16 + lr;
#pragma unroll
      for (int kc = 0; kc < 2; kc++)
        bfr[n][kc] = *(const bf16x8*)(lb + swz128(r, kc * 4 + lhi));
    }
#pragma unroll
    for (int kc = 0; kc < 2; kc++)
#pragma unroll
      for (int m = 0; m < 4; m++)
#pragma unroll
        for (int n = 0; n < 4; n++)
          acc[m][n] =
              __builtin_amdgcn_mfma_f32_16x16x32_bf16(af[m][kc], bfr[n][kc], acc[m][n], 0, 0, 0);
  }

  if (MODE == 2 && n0 >= 2048) {
    // V third: write transposed to vT (block rows never straddle batch: 2048 % 128 == 0)
    int bb = m0 >> 11;
    int tb = (m0 & 2047) + wr * 64 + lhi * 4;
#pragma unroll
    for (int n = 0; n < 4; n++) {
      int vcol = (n0 - 2048) + wc * 64 + n * 16 + lr;
      __bf16* vp = vT + ((size_t)bb * 1024 + vcol) * T_;
#pragma unroll
      for (int m = 0; m < 4; m++) {
        bf16x4 pv;
#pragma unroll
        for (int i = 0; i < 4; i++) pv[i] = (__bf16)acc[m][n][i];
        *(bf16x4*)(vp + tb + m * 16) = pv;
      }
    }
    return;
  }

  float oscale = (MODE == 2 && n0 < 1024) ? SCALE_LOG2E : 1.0f;
#pragma unroll
  for (int m = 0; m < 4; m++)
#pragma unroll
    for (int n = 0; n < 4; n++)
#pragma unroll
      for (int i = 0; i < 4; i++) {
        int rg = m0 + wr * 64 + m * 16 + lhi * 4 + i;
        int cg2 = n0 + wc * 64 + n * 16 + lr;
        if (MODE == 1)
          Cf[(size_t)rg * N + cg2] = acc[m][n][i];
        else
          Cb[(size_t)rg * N + cg2] = (__bf16)(acc[m][n][i] * oscale);
      }
}

// ---------------- causal flash attention, swapped-QK^T 32x32, double-buffered ----------------
// 1024 blocks; wave owns 32 q rows, lane owns 1 q row (full P row in regs).
// Q is pre-scaled by SCALE_LOG2E (folded into GEMM1 epilogue) -> scores already in log2 units.
__global__ __launch_bounds__(256) void attn_kernel(const __bf16* __restrict__ qkv,
                                                   const __bf16* __restrict__ vT,
                                                   __bf16* __restrict__ y) {
  __shared__ __align__(16) char lds[2][16384];  // [buf][ K(8KB,[kv][d]) | V^T(8KB,[d][kv]) ]
  int tid = threadIdx.x, w = tid >> 6, l = tid & 63;

  // work-balance map: 4 co-resident blocks per CU (bids mod-256 apart) sum to const work;
  // all qb of one bh share an XCD (bid&7 == bh&7) for K/V L2 reuse.
  int g = blockIdx.x >> 6, bh = blockIdx.x & 63;
  int q2 = g >> 2;
  int qb = (q2 & 1) ? ((q2 == 1) ? g + 4 : g - 12) : (15 - g);
  int b = bh >> 4, h = bh & 15;
  size_t base = (size_t)b * T_ * C3;
  int lq = l & 31, hi = l >> 5;
  int qrow = qb * 128 + w * 32 + lq;
  int q0w = qb * 128 + w * 32;

  // staging source pointers (pre-swizzled chunk)
  int lrow = l >> 3;
  int cg = (l & 7) ^ (lrow & 7);
  const __bf16* kptr = qkv + base + (size_t)(w * 16 + lrow) * C3 + C_ + h * D_ + cg * 8;
  const __bf16* vptr = vT + ((size_t)bh * D_ + w * 16 + lrow) * T_ + cg * 8;

  // Q as B-operand fragments (pre-scaled)
  bf16x8 qf[4];
  {
    const __bf16* qp = qkv + base + (size_t)qrow * C3 + h * D_;
#pragma unroll
    for (int c = 0; c < 4; c++) qf[c] = *(const bf16x8*)(qp + c * 16 + hi * 8);
  }

  f32x16 zacc;
#pragma unroll
  for (int i = 0; i < 16; i++) zacc[i] = 0.f;
  f32x16 o[2];
  o[0] = zacc; o[1] = zacc;
  float mrun = -__builtin_inff(), lrun = 0.f;

  int nt = 2 * qb + 2;

  // prologue: stage tile 0 into buf 0
  {
    char* kb = &lds[0][0];
    char* vb = &lds[0][8192];
    gload_lds16(kptr, kb + w * 2048);
    gload_lds16(kptr + 8 * C3, kb + w * 2048 + 1024);
    gload_lds16(vptr, vb + w * 2048);
    gload_lds16(vptr + 8 * T_, vb + w * 2048 + 1024);
  }

  for (int kt = 0; kt < nt; kt++) {
    int buf = kt & 1;
    __syncthreads();  // drains my stage of buf[kt&1]; all waves done reading buf^1
    if (kt + 1 < nt) {
      char* kb = &lds[buf ^ 1][0];
      char* vb = &lds[buf ^ 1][8192];
      const __bf16* kp = kptr + (size_t)(kt + 1) * 64 * C3;
      const __bf16* vp = vptr + (kt + 1) * 64;
      gload_lds16(kp, kb + w * 2048);
      gload_lds16(kp + 8 * C3, kb + w * 2048 + 1024);
      gload_lds16(vp, vb + w * 2048);
      gload_lds16(vp + 8 * T_, vb + w * 2048 + 1024);
    }
    if (kt * 64 > q0w + 31) continue;  // wave fully below this kv tile
    char* kb = &lds[buf][0];
    char* vb = &lds[buf][8192];

    // S^T[kv][q] = K · Q^T : lane holds 32 kv values of its q row (log2 units)
    f32x16 s[2];
    __builtin_amdgcn_s_setprio(1);
#pragma unroll
    for (int b2 = 0; b2 < 2; b2++) {
      bf16x8 kf0 = *(const bf16x8*)(kb + swz128(b2 * 32 + lq, hi));
      s[b2] = __builtin_amdgcn_mfma_f32_32x32x16_bf16(kf0, qf[0], zacc, 0, 0, 0);
#pragma unroll
      for (int c = 1; c < 4; c++) {
        bf16x8 kf = *(const bf16x8*)(kb + swz128(b2 * 32 + lq, 2 * c + hi));
        s[b2] = __builtin_amdgcn_mfma_f32_32x32x16_bf16(kf, qf[c], s[b2], 0, 0, 0);
      }
    }
    __builtin_amdgcn_s_setprio(0);

    // causal mask (diagonal-straddling tiles only)
    if (kt * 64 + 63 > q0w) {
#pragma unroll
      for (int b2 = 0; b2 < 2; b2++)
#pragma unroll
        for (int r = 0; r < 16; r++) {
          int kv = kt * 64 + b2 * 32 + ((r & 3) + 8 * (r >> 2)) + 4 * hi;
          if (kv > qrow) s[b2][r] = -1e30f;
        }
    }

    // row max: max3 tree (17 ops) + one cross-half swap
    {
      auto xi = [&](int i) -> float { return i < 16 ? s[0][i] : s[1][i - 16]; };
      float t10[11];
#pragma unroll
      for (int g3 = 0; g3 < 10; g3++) t10[g3] = fmax3(xi(3 * g3), xi(3 * g3 + 1), xi(3 * g3 + 2));
      t10[10] = fmaxf(xi(30), xi(31));
      float u0 = fmax3(t10[0], t10[1], t10[2]);
      float u1 = fmax3(t10[3], t10[4], t10[5]);
      float u2 = fmax3(t10[6], t10[7], t10[8]);
      float u3 = fmaxf(t10[9], t10[10]);
      float tl = fmaxf(fmax3(u0, u1, u2), u3);
      float tmax = fmaxf(tl, __shfl_xor(tl, 32));

      // defer-max (T13): only rescale when some lane's max grew past threshold
      if (!__all(tmax - mrun <= 8.0f)) {
        float mnew = fmaxf(mrun, tmax);
        float al = __builtin_amdgcn_exp2f(mrun - mnew);
        mrun = mnew;
        lrun *= al;
#pragma unroll
        for (int d = 0; d < 2; d++)
#pragma unroll
          for (int i = 0; i < 16; i++) o[d][i] *= al;
      }
    }

    // p = 2^(s - m)
#pragma unroll
    for (int b2 = 0; b2 < 2; b2++)
#pragma unroll
      for (int r = 0; r < 16; r++) s[b2][r] = __builtin_amdgcn_exp2f(s[b2][r] - mrun);

    // row sum: packed-f32 tree (15 pk_add) + one cross-half swap
    {
      f32x2 p8[8];
#pragma unroll
      for (int g3 = 0; g3 < 8; g3++) {
        f32x2 a = {s[0][2 * g3], s[0][2 * g3 + 1]};
        f32x2 b2v = {s[1][2 * g3], s[1][2 * g3 + 1]};
        p8[g3] = pk_add(a, b2v);
      }
#pragma unroll
      for (int g3 = 0; g3 < 4; g3++) p8[g3] = pk_add(p8[g3], p8[g3 + 4]);
      p8[0] = pk_add(p8[0], p8[2]);
      p8[1] = pk_add(p8[1], p8[3]);
      p8[0] = pk_add(p8[0], p8[1]);
      float rs = p8[0][0] + p8[0][1];
      lrun += rs + __shfl_xor(rs, 32);
    }

    // P^T -> B-operand fragments via cvt_pk + permlane32_swap (no LDS)
    bf16x8 pa[4];
#pragma unroll
    for (int b2 = 0; b2 < 2; b2++) {
      unsigned wg[4][2];
#pragma unroll
      for (int gg = 0; gg < 4; gg++) {
        wg[gg][0] = cvt_pk_bf16(s[b2][4 * gg + 0], s[b2][4 * gg + 1]);
        wg[gg][1] = cvt_pk_bf16(s[b2][4 * gg + 2], s[b2][4 * gg + 3]);
      }
#pragma unroll
      for (int cp = 0; cp < 2; cp++) {
        unsigned x0 = wg[2 * cp][0], x1 = wg[2 * cp][1];
        unsigned y0 = wg[2 * cp + 1][0], y1 = wg[2 * cp + 1][1];
        pl32swap(x0, y0);
        pl32swap(x1, y1);
        union { u32x4 u; bf16x8 hh; } uu;
        uu.u = (u32x4){x0, x1, y0, y1};
        pa[b2 * 2 + cp] = uu.hh;
      }
    }

    // O^T[d][q] += V^T · P^T
    __builtin_amdgcn_s_setprio(1);
#pragma unroll
    for (int db = 0; db < 2; db++)
#pragma unroll
      for (int c = 0; c < 4; c++) {
        bf16x8 vf = *(const bf16x8*)(vb + swz128(db * 32 + lq, 2 * c + hi));
        o[db] = __builtin_amdgcn_mfma_f32_32x32x16_bf16(vf, pa[c], o[db], 0, 0, 0);
      }
    __builtin_amdgcn_s_setprio(0);
  }

  // epilogue: lane owns q-row qrow; d = db*32 + 8*rr + 4*hi + i
  float inv = 1.f / lrun;
  __bf16* yp = y + (size_t)(b * T_ + qrow) * C_ + h * D_;
#pragma unroll
  for (int db = 0; db < 2; db++)
#pragma unroll
    for (int rr = 0; rr < 4; rr++) {
      bf16x4 ov;
#pragma unroll
      for (int i = 0; i < 4; i++) ov[i] = (__bf16)(o[db][rr * 4 + i] * inv);
      *(bf16x4*)(yp + db * 32 + rr * 8 + hi * 4) = ov;
    }
}

extern "C" void kernel_launch(void* const* d_in, const int* in_sizes, int n_in,
                              void* d_out, int out_size, void* d_ws, size_t ws_size,
                              hipStream_t stream) {
  const float* x = (const float*)d_in[0];
  const float* Wa = (const float*)d_in[1];
  const float* Wp = (const float*)d_in[2];
  float* out = (float*)d_out;
  char* ws = (char*)d_ws;

  // xb and yb share storage (xb dead after GEMM1, yb born after GEMM1)
  __bf16* xb  = (__bf16*)(ws);                 // 16 MB
  __bf16* yb  = (__bf16*)(ws);                 // 16 MB (aliases xb)
  __bf16* wat = (__bf16*)(ws + 16777216);      // 6 MB
  __bf16* wpt = (__bf16*)(ws + 23068672);      // 2 MB
  __bf16* qkv = (__bf16*)(ws + 25165824);      // 48 MB (V third unused)
  __bf16* vT  = (__bf16*)(ws + 75497472);      // 16 MB

  prep_kernel<<<12288, 256, 0, stream>>>(x, Wa, Wp, xb, wat, wpt);

  // qkv = x @ W_attn; Q cols pre-scaled, V cols written transposed to vT
  gemm_bt_kernel<2><<<dim3(C3 / 128, (B_ * T_) / 128), 256, 0, stream>>>(
      xb, wat, qkv, nullptr, vT, B_ * T_, C3, C_);

  attn_kernel<<<dim3(1024), 256, 0, stream>>>(qkv, vT, yb);

  gemm_bt_kernel<1><<<dim3(C_ / 128, (B_ * T_) / 128), 256, 0, stream>>>(
      yb, wpt, nullptr, out, nullptr, B_ * T_, C_, C_);
}